// Round 3
// baseline (344.607 us; speedup 1.0000x reference)
//
#include <hip/hip_runtime.h>

#define U_ROWS 20000
#define I_COLS 10000
#define LDI    10001
#define B_N    4096
#define SU     313   // ceil(10000/32) K-steps for u-gemm
#define SC     625   // 20000/32 K-steps for c-gemm

typedef __attribute__((ext_vector_type(8))) __bf16 bf16x8;
typedef __attribute__((ext_vector_type(4))) float f32x4;

__device__ __forceinline__ unsigned short f2bf(float f) {
    unsigned int u = __float_as_uint(f);
    return (unsigned short)((u + 0x7FFFu + ((u >> 16) & 1u)) >> 16);  // RTN-even
}

// Fused prep:
//  - pack W_u, W_i into MFMA B-fragment order (bf16)
//  - transpose MLP weights (fp32)
//  - transposed fp32 copies WuT [I][64], WiT [U][64] for coalesced epilogue gathers
__global__ __launch_bounds__(256) void k_prep(
    const float* __restrict__ Wu, const float* __restrict__ Wi,
    unsigned short* __restrict__ Pu, unsigned short* __restrict__ Pi,
    const float* __restrict__ W1, const float* __restrict__ W2, const float* __restrict__ W3,
    float* __restrict__ Wt1, float* __restrict__ Wt2, float* __restrict__ Wt3,
    float* __restrict__ WuT, float* __restrict__ WiT)
{
    const int NU = SU * 2048, NC2 = SC * 2048;
    int idx = blockIdx.x * 256 + threadIdx.x;
    if (idx < NU + NC2) {
        const float* W = (idx < NU) ? Wu : Wi;
        unsigned short* out = (idx < NU) ? Pu : Pi;
        int n_k = (idx < NU) ? I_COLS : U_ROWS;
        int li = (idx < NU) ? idx : idx - NU;
        int j  = li & 7;
        int l  = (li >> 3) & 63;
        int nb = (li >> 9) & 3;
        int s  = li >> 11;
        int n  = nb * 16 + (l & 15);
        int k  = s * 32 + ((l >> 4) << 3) + j;
        float v = (k < n_k) ? W[(size_t)n * n_k + k] : 0.0f;
        out[li] = f2bf(v);
        return;
    }
    int r2 = idx - (NU + NC2);
    if (r2 < 64 * 128) { int r = r2 / 128, c = r2 % 128; Wt1[c * 64 + r] = W1[r2]; return; }
    r2 -= 64 * 128;
    if (r2 < 32 * 64)  { int r = r2 / 64,  c = r2 % 64;  Wt2[c * 32 + r] = W2[r2]; return; }
    r2 -= 32 * 64;
    if (r2 < 16 * 32)  { int r = r2 / 32,  c = r2 % 32;  Wt3[c * 16 + r] = W3[r2]; return; }
    r2 -= 16 * 32;
    if (r2 < 64 * I_COLS) {           // WuT[k][n] = Wu[n][k], coalesced read
        int n = r2 / I_COLS, k = r2 % I_COLS;
        WuT[(size_t)k * 64 + n] = Wu[r2];
        return;
    }
    r2 -= 64 * I_COLS;
    if (r2 < 64 * U_ROWS) {           // WiT[u][n] = Wi[n][u]
        int n = r2 / U_ROWS, u = r2 % U_ROWS;
        WiT[(size_t)u * 64 + n] = Wi[r2];
        return;
    }
}

// Fused GEMM, LDS-free: each lane loads its MFMA A-fragment elements directly
// from global (coalesced by construction), packs to bf16, MFMAs.
//  blocks [0, 157*NC):   Cpart[p][i][n] = sum_{u in K-range p} A[u,i]*Wi[n,u]
//  blocks [+, +64*NP):   Upart[p][r][n] = sum_{i in K-range p} A[u_r,i]*Wu[n,i]
// p = bid % NC so that with NC==8, p == XCD (round-robin) -> per-XCD L2 keeps
// its own packed-B K-slice.
__global__ __launch_bounds__(256) void k_gemm(
    const float* __restrict__ A, const int* __restrict__ uidx,
    const unsigned short* __restrict__ Bpu, const unsigned short* __restrict__ Bpc,
    float* __restrict__ Upart, float* __restrict__ Cpart,
    int spu, int spc, int NC)
{
    const int t = threadIdx.x, lane = t & 63, w = t >> 6;
    const int rl = lane & 15, g = lane >> 4;
    const int CB = 157 * NC;
    const char* Ab = (const char*)A;

    f32x4 acc[4];
#pragma unroll
    for (int nb = 0; nb < 4; ++nb) acc[nb] = (f32x4)(0.0f);

    if ((int)blockIdx.x < CB) {
        // ---------------- c-gemm: M=i, K=u ----------------
        const int p = blockIdx.x % NC, mb = blockIdx.x / NC;
        const int i0 = mb * 64;
        const int ci = i0 + w * 16 + rl;               // this lane's M column
        const int ci_eff = (ci < I_COLS) ? ci : 0;     // clamp; junk rows are discarded at write
        const int s0 = p * spc;
        const int s1 = (SC < s0 + spc) ? SC : (s0 + spc);

        unsigned int off[8];
#pragma unroll
        for (int j = 0; j < 8; ++j)
            off[j] = (unsigned int)(((s0 * 32 + g * 8 + j) * LDI + ci_eff) * 4);

#define CLOADP(dst) do { \
        _Pragma("unroll") \
        for (int j_ = 0; j_ < 8; ++j_) { \
            dst[j_] = *(const float*)(Ab + off[j_]); \
            off[j_] += 32u * LDI * 4u; \
        } } while (0)

        float av[8];
        CLOADP(av);
        for (int s = s0; s < s1; ++s) {
            float nx[8];
            if (s + 1 < s1) { CLOADP(nx); }
            else {
#pragma unroll
                for (int j = 0; j < 8; ++j) nx[j] = 0.0f;
            }
            bf16x8 bv[4];
#pragma unroll
            for (int nb = 0; nb < 4; ++nb)
                bv[nb] = *(const bf16x8*)(Bpc + ((size_t)(s * 4 + nb) * 64 + lane) * 8);
            union { int i[4]; bf16x8 v; } af;
#pragma unroll
            for (int q = 0; q < 4; ++q)
                af.i[q] = __builtin_amdgcn_perm(__float_as_uint(av[2 * q + 1]),
                                                __float_as_uint(av[2 * q]), 0x07060302);
#pragma unroll
            for (int nb = 0; nb < 4; ++nb)
                acc[nb] = __builtin_amdgcn_mfma_f32_16x16x32_bf16(af.v, bv[nb], acc[nb], 0, 0, 0);
#pragma unroll
            for (int j = 0; j < 8; ++j) av[j] = nx[j];
        }

        float* outp = Cpart + (size_t)p * I_COLS * 64;
#pragma unroll
        for (int nb = 0; nb < 4; ++nb)
#pragma unroll
            for (int reg = 0; reg < 4; ++reg) {
                int i = i0 + w * 16 + g * 4 + reg;
                if (i < I_COLS) outp[(size_t)i * 64 + nb * 16 + rl] = acc[nb][reg];
            }
    } else {
        // ---------------- u-gemm: M=batch row, K=i ----------------
        const int bid = blockIdx.x - CB;
        const int p = bid % NC, mb = bid / NC;
        const int r0 = mb * 64;
        const int s0 = p * spu;
        const int s1 = (SU < s0 + spu) ? SU : (s0 + spu);

        const int ur = uidx[r0 + w * 16 + rl];         // this lane's user row
        unsigned int offu = (unsigned int)(((size_t)ur * LDI + s0 * 32 + g * 8) * 4);

        union F8 { float f[8]; f32x4 v[2]; };
#define ULOADP(dst, S) do { \
        int kb_ = (S) * 32 + g * 8; \
        dst.v[0] = (kb_     < I_COLS) ? *(const f32x4*)(Ab + offu)      : (f32x4)(0.0f); \
        dst.v[1] = (kb_ + 4 < I_COLS) ? *(const f32x4*)(Ab + offu + 16) : (f32x4)(0.0f); \
        offu += 128u; } while (0)

        F8 av;
        ULOADP(av, s0);
        for (int s = s0; s < s1; ++s) {
            F8 nx;
            if (s + 1 < s1) { ULOADP(nx, s + 1); }
            else {
#pragma unroll
                for (int j = 0; j < 8; ++j) nx.f[j] = 0.0f;
            }
            bf16x8 bv[4];
#pragma unroll
            for (int nb = 0; nb < 4; ++nb)
                bv[nb] = *(const bf16x8*)(Bpu + ((size_t)(s * 4 + nb) * 64 + lane) * 8);
            union { int i[4]; bf16x8 v; } af;
#pragma unroll
            for (int q = 0; q < 4; ++q)
                af.i[q] = __builtin_amdgcn_perm(__float_as_uint(av.f[2 * q + 1]),
                                                __float_as_uint(av.f[2 * q]), 0x07060302);
#pragma unroll
            for (int nb = 0; nb < 4; ++nb)
                acc[nb] = __builtin_amdgcn_mfma_f32_16x16x32_bf16(af.v, bv[nb], acc[nb], 0, 0, 0);
#pragma unroll
            for (int j = 0; j < 8; ++j) av.f[j] = nx.f[j];
        }

        float* outp = Upart + (size_t)p * B_N * 64;
#pragma unroll
        for (int nb = 0; nb < 4; ++nb)
#pragma unroll
            for (int reg = 0; reg < 4; ++reg) {
                int r = r0 + w * 16 + g * 4 + reg;
                outp[(size_t)r * 64 + nb * 16 + rl] = acc[nb][reg];
            }
    }
}

__device__ __forceinline__ float redsum64(float x) {
    x += __shfl_xor(x, 1);  x += __shfl_xor(x, 2);  x += __shfl_xor(x, 4);
    x += __shfl_xor(x, 8);  x += __shfl_xor(x, 16); x += __shfl_xor(x, 32);
    return x;
}
__device__ __forceinline__ float redsum32(float x) {
    x += __shfl_xor(x, 1); x += __shfl_xor(x, 2); x += __shfl_xor(x, 4);
    x += __shfl_xor(x, 8); x += __shfl_xor(x, 16);
    return x;
}
__device__ __forceinline__ float redsum16(float x) {
    x += __shfl_xor(x, 1); x += __shfl_xor(x, 2); x += __shfl_xor(x, 4);
    x += __shfl_xor(x, 8);
    return x;
}

// one wave per batch row: reduce partials, mask corrections, full MLP
__global__ __launch_bounds__(256) void k_epi(
    const float* __restrict__ A, const int* __restrict__ uidx, const int* __restrict__ iidx,
    const float* __restrict__ Upart, const float* __restrict__ Cpart, int NP, int NC,
    const float* __restrict__ WuT, const float* __restrict__ WiT,
    const float* __restrict__ Wt1, const float* __restrict__ b1, const float* __restrict__ g1, const float* __restrict__ be1,
    const float* __restrict__ Wt2, const float* __restrict__ b2, const float* __restrict__ g2, const float* __restrict__ be2,
    const float* __restrict__ Wt3, const float* __restrict__ b3, const float* __restrict__ g3, const float* __restrict__ be3,
    const float* __restrict__ Wp, const float* __restrict__ bp,
    float* __restrict__ out)
{
    const int t = threadIdx.x, lane = t & 63, w = t >> 6;
    const int r = blockIdx.x * 4 + w;
    const int u = uidx[r], it = iidx[r];
    const float a_ui = A[(size_t)u * LDI + it];

    float ue = 0.f, ie = 0.f;
    for (int p0 = 0; p0 < NP; ++p0) ue += Upart[((size_t)p0 * B_N + r) * 64 + lane];
    for (int p0 = 0; p0 < NC; ++p0) ie += Cpart[((size_t)p0 * I_COLS + it) * 64 + lane];
    ue -= a_ui * WuT[(size_t)it * 64 + lane];
    ie -= a_ui * WiT[(size_t)u * 64 + lane];

    // layer 1: 128 -> 64, LN, ReLU
    float h = b1[lane];
    for (int c = 0; c < 64; ++c) h += __shfl(ue, c) * Wt1[c * 64 + lane];
    for (int c = 0; c < 64; ++c) h += __shfl(ie, c) * Wt1[(64 + c) * 64 + lane];
    {
        float m = redsum64(h) * (1.0f / 64.0f);
        float d = h - m;
        float v = redsum64(d * d) * (1.0f / 64.0f);
        h = d * rsqrtf(v + 1e-5f) * g1[lane] + be1[lane];
        h = fmaxf(h, 0.0f);
    }
    // layer 2: 64 -> 32
    const int l2 = lane & 31;
    float h2 = b2[l2];
    for (int c = 0; c < 64; ++c) h2 += __shfl(h, c) * Wt2[c * 32 + l2];
    {
        float m = redsum32(h2) * (1.0f / 32.0f);
        float d = h2 - m;
        float v = redsum32(d * d) * (1.0f / 32.0f);
        h2 = d * rsqrtf(v + 1e-5f) * g2[l2] + be2[l2];
        h2 = fmaxf(h2, 0.0f);
    }
    // layer 3: 32 -> 16
    const int l3 = lane & 15;
    float h3 = b3[l3];
    for (int c = 0; c < 32; ++c) h3 += __shfl(h2, c) * Wt3[c * 16 + l3];
    {
        float m = redsum16(h3) * (1.0f / 16.0f);
        float d = h3 - m;
        float v = redsum16(d * d) * (1.0f / 16.0f);
        h3 = d * rsqrtf(v + 1e-5f) * g3[l3] + be3[l3];
        h3 = fmaxf(h3, 0.0f);
    }
    float tt = h3 * Wp[l3];
    tt = redsum16(tt);
    if (lane == 0) out[r] = tt + bp[0];
}

extern "C" void kernel_launch(void* const* d_in, const int* in_sizes, int n_in,
                              void* d_out, int out_size, void* d_ws, size_t ws_size,
                              hipStream_t stream)
{
    const float* A    = (const float*)d_in[0];
    const int*   uidx = (const int*)d_in[1];
    const int*   iidx = (const int*)d_in[2];
    const float* W_u  = (const float*)d_in[3];
    const float* W_i  = (const float*)d_in[4];
    const float* W1   = (const float*)d_in[5];
    const float* b1   = (const float*)d_in[6];
    const float* g1   = (const float*)d_in[7];
    const float* be1  = (const float*)d_in[8];
    const float* W2   = (const float*)d_in[9];
    const float* b2   = (const float*)d_in[10];
    const float* g2   = (const float*)d_in[11];
    const float* be2  = (const float*)d_in[12];
    const float* W3   = (const float*)d_in[13];
    const float* b3   = (const float*)d_in[14];
    const float* g3   = (const float*)d_in[15];
    const float* be3  = (const float*)d_in[16];
    const float* Wp   = (const float*)d_in[17];
    const float* bp   = (const float*)d_in[18];
    float* out = (float*)d_out;

    unsigned short* Wtu_p = (unsigned short*)d_ws;        // SU*2048 bf16
    unsigned short* Wti_p = Wtu_p + (size_t)SU * 2048;    // SC*2048 bf16
    float* Wt1 = (float*)(Wti_p + (size_t)SC * 2048);     // 128*64
    float* Wt2 = Wt1 + 128 * 64;                          // 64*32
    float* Wt3 = Wt2 + 64 * 32;                           // 32*16
    float* WuT = Wt3 + 32 * 16;                           // I_COLS*64
    float* WiT = WuT + (size_t)I_COLS * 64;               // U_ROWS*64
    float* Upart = WiT + (size_t)U_ROWS * 64;

    size_t fixed_b = (size_t)(SU + SC) * 2048 * 2
                   + (size_t)(128 * 64 + 64 * 32 + 32 * 16) * 4
                   + (size_t)(I_COLS + U_ROWS) * 64 * 4;
    int NP = 8, NC = 8;
    while (NP > 1 &&
           fixed_b + (size_t)NP * B_N * 64 * 4 + (size_t)NC * I_COLS * 64 * 4 > ws_size) {
        NP >>= 1; NC >>= 1;
    }
    float* Cpart = Upart + (size_t)NP * B_N * 64;

    int spu = (SU + NP - 1) / NP;
    int spc = (SC + NC - 1) / NC;

    int prep_tot = (SU + SC) * 2048 + 64 * 128 + 32 * 64 + 16 * 32
                 + 64 * I_COLS + 64 * U_ROWS;
    hipLaunchKernelGGL(k_prep, dim3((prep_tot + 255) / 256), dim3(256), 0, stream,
                       W_u, W_i, Wtu_p, Wti_p, W1, W2, W3, Wt1, Wt2, Wt3, WuT, WiT);

    hipLaunchKernelGGL(k_gemm, dim3(157 * NC + 64 * NP), dim3(256), 0, stream,
                       A, uidx, Wtu_p, Wti_p, Upart, Cpart, spu, spc, NC);

    hipLaunchKernelGGL(k_epi, dim3(B_N / 4), dim3(256), 0, stream,
                       A, uidx, iidx, Upart, Cpart, NP, NC,
                       WuT, WiT, Wt1, b1, g1, be1, Wt2, b2, g2, be2,
                       Wt3, b3, g3, be3, Wp, bp, out);
}

// Round 4
// 332.364 us; speedup vs baseline: 1.0368x; 1.0368x over previous
//
#include <hip/hip_runtime.h>

#define U_ROWS 20000
#define I_COLS 10000
#define LDI    10001
#define B_N    4096
#define SC     625        // K-steps of 32 u-rows for c-gemm (20000/32)
#define SUT    79         // tile-steps of 128 i-cols for u-gemm (ceil(10000/128))
#define SU_P   316        // packed 32-k-steps for u-gemm (79*4)
#define NPAN   40         // i-panels of 256 for c-gemm
#define NP_U   8          // K-split for u-gemm
#define SPU    10         // ceil(SUT/NP_U)

typedef __attribute__((ext_vector_type(8))) __bf16 bf16x8;
typedef __attribute__((ext_vector_type(4))) float f32x4;

__device__ __forceinline__ unsigned short f2bf(float f) {
    unsigned int u = __float_as_uint(f);
    return (unsigned short)((u + 0x7FFFu + ((u >> 16) & 1u)) >> 16);  // RTN-even
}

// Fused prep: pack W_u/W_i into MFMA B-fragment order (bf16), transpose MLP
// weights, and make transposed WuT/WiT for the coalesced epilogue gather.
// Pack layout: out[((s*4+nb)*64 + l)*8 + j] = bf16(W[nb*16+(l&15)][s*32+(l>>4)*8+j])
__global__ __launch_bounds__(256) void k_prep(
    const float* __restrict__ Wu, const float* __restrict__ Wi,
    unsigned short* __restrict__ Pu, unsigned short* __restrict__ Pi,
    const float* __restrict__ W1, const float* __restrict__ W2, const float* __restrict__ W3,
    float* __restrict__ Wt1, float* __restrict__ Wt2, float* __restrict__ Wt3,
    float* __restrict__ WuT, float* __restrict__ WiT)
{
    const int NU = SU_P * 2048, NC2 = SC * 2048;
    int idx = blockIdx.x * 256 + threadIdx.x;
    if (idx < NU + NC2) {
        const float* W = (idx < NU) ? Wu : Wi;
        unsigned short* out = (idx < NU) ? Pu : Pi;
        int n_k = (idx < NU) ? I_COLS : U_ROWS;
        int li = (idx < NU) ? idx : idx - NU;
        int j  = li & 7;
        int l  = (li >> 3) & 63;
        int nb = (li >> 9) & 3;
        int s  = li >> 11;
        int n  = nb * 16 + (l & 15);
        int k  = s * 32 + ((l >> 4) << 3) + j;
        float v = (k < n_k) ? W[(size_t)n * n_k + k] : 0.0f;
        out[li] = f2bf(v);
        return;
    }
    int r2 = idx - (NU + NC2);
    if (r2 < 64 * 128) { int r = r2 / 128, c = r2 % 128; Wt1[c * 64 + r] = W1[r2]; return; }
    r2 -= 64 * 128;
    if (r2 < 32 * 64)  { int r = r2 / 64,  c = r2 % 64;  Wt2[c * 32 + r] = W2[r2]; return; }
    r2 -= 32 * 64;
    if (r2 < 16 * 32)  { int r = r2 / 32,  c = r2 % 32;  Wt3[c * 16 + r] = W3[r2]; return; }
    r2 -= 16 * 32;
    if (r2 < 64 * I_COLS) {
        int n = r2 / I_COLS, k = r2 % I_COLS;
        WuT[(size_t)k * 64 + n] = Wu[r2];
        return;
    }
    r2 -= 64 * I_COLS;
    if (r2 < 64 * U_ROWS) {
        int n = r2 / U_ROWS, u = r2 % U_ROWS;
        WiT[(size_t)u * 64 + n] = Wi[r2];
        return;
    }
}

// Fused GEMM, wide-burst LDS staging, 1-step register prefetch.
//  blocks [0, NPAN*NC):    c-gemm  Cpart[p][i][n] = sum_u A[u,i]*Wi[n,u]
//    tile [32u x 256i] f32 (32KB LDS), 1KB contiguous per A-row per step.
//  blocks [NPAN*NC, +64*NP_U): u-gemm  Upart[p][r][n] = sum_i A[u_r,i]*Wu[n,i]
//    tile [64r x 128k] f32 (32KB LDS), 512B contiguous per row per step.
// LDS swizzles (4-float granularity XOR) are bank-uniform on both the write
// and read side (see derivations in-line).
__global__ __launch_bounds__(256) void k_gemm(
    const float* __restrict__ A, const int* __restrict__ uidx,
    const unsigned short* __restrict__ Bpu, const unsigned short* __restrict__ Bpc,
    float* __restrict__ Upart, float* __restrict__ Cpart,
    int NC, int spc)
{
    __shared__ float At[32 * 256];      // 32 KB, reused by both paths
    const int t = threadIdx.x, lane = t & 63, w = t >> 6;
    const int rl = lane & 15, g = lane >> 4;
    const int CB = NPAN * NC;

    if ((int)blockIdx.x < CB) {
        // ---------------- c-gemm ----------------
        const int p = blockIdx.x % NC, mb = blockIdx.x / NC;
        const int i0 = mb * 256;
        const int s0 = p * spc;
        const int s1 = (SC < s0 + spc) ? SC : (s0 + spc);
        const int ul = t & 31, ch = t >> 5;          // stage: row ul, col-chunk ch
        const int cbase = i0 + ch * 32;
        // write swizzle: col c -> c ^ ((ul&7)<<2) ^ (((ul>>3)&1)<<4)
        //  write banks (fixed q): 4q ^ 4*(ul&7) ^ 16*((ul>>3)&1) -> 8 groups x 4 banks, uniform
        const int wmask = ((ul & 7) << 2) ^ (((ul >> 3) & 1) << 4);
        float* wp = At + ul * 256;

        f32x4 acc[4][4];
#pragma unroll
        for (int mt = 0; mt < 4; ++mt)
#pragma unroll
            for (int nb = 0; nb < 4; ++nb) acc[mt][nb] = (f32x4)(0.0f);

        f32x4 av[8];
        {
            const float* src = A + (size_t)(s0 * 32 + ul) * LDI + cbase;
#pragma unroll
            for (int q = 0; q < 8; ++q) av[q] = *(const f32x4*)(src + q * 4);
        }
        for (int s = s0; s < s1; ++s) {
            __syncthreads();            // prev step's LDS reads done
#pragma unroll
            for (int q = 0; q < 8; ++q) {
                int c0 = ch * 32 + q * 4;
                *(f32x4*)(wp + (c0 ^ wmask)) = av[q];
            }
            __syncthreads();            // tile visible
            if (s + 1 < s1) {
                const float* src = A + (size_t)((s + 1) * 32 + ul) * LDI + cbase;
#pragma unroll
                for (int q = 0; q < 8; ++q) av[q] = *(const f32x4*)(src + q * 4);
            }
            bf16x8 bv[4];
#pragma unroll
            for (int nb = 0; nb < 4; ++nb)
                bv[nb] = *(const bf16x8*)(Bpc + ((size_t)(s * 4 + nb) * 64 + lane) * 8);
            // read: element (u_l = g*8+j, col cl): swz = cl ^ (j<<2) ^ ((g&1)<<4)
            //  banks (fixed mt,j): rl bits0-3, (g&1) bit4 -> 32 banks, 2-way (free)
#pragma unroll
            for (int mt = 0; mt < 4; ++mt) {
                const int cl = w * 64 + mt * 16 + rl;
                unsigned int au[8];
#pragma unroll
                for (int j = 0; j < 8; ++j) {
                    int swz = cl ^ (j << 2) ^ ((g & 1) << 4);
                    au[j] = __float_as_uint(At[(g * 8 + j) * 256 + swz]);
                }
                union { int i[4]; bf16x8 v; } af;
#pragma unroll
                for (int q = 0; q < 4; ++q)
                    af.i[q] = __builtin_amdgcn_perm(au[2 * q + 1], au[2 * q], 0x07060302);
#pragma unroll
                for (int nb = 0; nb < 4; ++nb)
                    acc[mt][nb] = __builtin_amdgcn_mfma_f32_16x16x32_bf16(af.v, bv[nb], acc[mt][nb], 0, 0, 0);
            }
        }

        float* outp = Cpart + (size_t)p * I_COLS * 64;
#pragma unroll
        for (int mt = 0; mt < 4; ++mt)
#pragma unroll
            for (int nb = 0; nb < 4; ++nb)
#pragma unroll
                for (int reg = 0; reg < 4; ++reg) {
                    int i = i0 + w * 64 + mt * 16 + g * 4 + reg;
                    if (i < I_COLS) outp[(size_t)i * 64 + nb * 16 + rl] = acc[mt][nb][reg];
                }
    } else {
        // ---------------- u-gemm ----------------
        const int bid = blockIdx.x - CB;
        const int p = bid % NP_U, mb = bid / NP_U;
        const int r0 = mb * 64;
        const int s0 = p * SPU;
        const int s1 = (SUT < s0 + SPU) ? SUT : (s0 + SPU);
        const int rt = t >> 2, ch = t & 3;           // stage: row rt, col-chunk ch
        const int urow = uidx[r0 + rt];
        const float* abase = A + (size_t)urow * LDI + ch * 32;
        // swizzle: col c -> c ^ ((row&7)<<2); bank-uniform both sides (b128)
        const int wmask = (rt & 7) << 2;
        float* wp = At + rt * 128;
        const int rloc = w * 16 + rl;
        const float* rp = At + rloc * 128;
        const int rmask = (rloc & 7) << 2;

        f32x4 acc[4];
#pragma unroll
        for (int nb = 0; nb < 4; ++nb) acc[nb] = (f32x4)(0.0f);

        f32x4 av[8];
        {
            const float* src = abase + s0 * 128;
#pragma unroll
            for (int q = 0; q < 8; ++q) av[q] = *(const f32x4*)(src + q * 4);
        }
        for (int s = s0; s < s1; ++s) {
            __syncthreads();
#pragma unroll
            for (int q = 0; q < 8; ++q) {
                int c0 = ch * 32 + q * 4;
                *(f32x4*)(wp + (c0 ^ wmask)) = av[q];
            }
            __syncthreads();
            if (s + 1 < s1) {
                const float* src = abase + (s + 1) * 128;
#pragma unroll
                for (int q = 0; q < 8; ++q) av[q] = *(const f32x4*)(src + q * 4);
            }
#pragma unroll
            for (int ks = 0; ks < 4; ++ks) {
                const int kk = s * 4 + ks;
                bf16x8 bv[4];
#pragma unroll
                for (int nb = 0; nb < 4; ++nb)
                    bv[nb] = *(const bf16x8*)(Bpu + ((size_t)(kk * 4 + nb) * 64 + lane) * 8);
                const int kb = ks * 32 + g * 8;
                f32x4 a0 = *(const f32x4*)(rp + (kb ^ rmask));
                f32x4 a1 = *(const f32x4*)(rp + ((kb + 4) ^ rmask));
                union { int i[4]; bf16x8 v; } af;
                af.i[0] = __builtin_amdgcn_perm(__float_as_uint(a0[1]), __float_as_uint(a0[0]), 0x07060302);
                af.i[1] = __builtin_amdgcn_perm(__float_as_uint(a0[3]), __float_as_uint(a0[2]), 0x07060302);
                af.i[2] = __builtin_amdgcn_perm(__float_as_uint(a1[1]), __float_as_uint(a1[0]), 0x07060302);
                af.i[3] = __builtin_amdgcn_perm(__float_as_uint(a1[3]), __float_as_uint(a1[2]), 0x07060302);
#pragma unroll
                for (int nb = 0; nb < 4; ++nb)
                    acc[nb] = __builtin_amdgcn_mfma_f32_16x16x32_bf16(af.v, bv[nb], acc[nb], 0, 0, 0);
            }
        }

        float* outp = Upart + (size_t)p * B_N * 64;
#pragma unroll
        for (int nb = 0; nb < 4; ++nb)
#pragma unroll
            for (int reg = 0; reg < 4; ++reg) {
                int r = r0 + w * 16 + g * 4 + reg;
                outp[(size_t)r * 64 + nb * 16 + rl] = acc[nb][reg];
            }
    }
}

__device__ __forceinline__ float redsum64(float x) {
    x += __shfl_xor(x, 1);  x += __shfl_xor(x, 2);  x += __shfl_xor(x, 4);
    x += __shfl_xor(x, 8);  x += __shfl_xor(x, 16); x += __shfl_xor(x, 32);
    return x;
}
__device__ __forceinline__ float redsum32(float x) {
    x += __shfl_xor(x, 1); x += __shfl_xor(x, 2); x += __shfl_xor(x, 4);
    x += __shfl_xor(x, 8); x += __shfl_xor(x, 16);
    return x;
}
__device__ __forceinline__ float redsum16(float x) {
    x += __shfl_xor(x, 1); x += __shfl_xor(x, 2); x += __shfl_xor(x, 4);
    x += __shfl_xor(x, 8);
    return x;
}

// one wave per batch row: reduce partials, mask corrections, full MLP
__global__ __launch_bounds__(256) void k_epi(
    const float* __restrict__ A, const int* __restrict__ uidx, const int* __restrict__ iidx,
    const float* __restrict__ Upart, const float* __restrict__ Cpart, int NP, int NC,
    const float* __restrict__ WuT, const float* __restrict__ WiT,
    const float* __restrict__ Wt1, const float* __restrict__ b1, const float* __restrict__ g1, const float* __restrict__ be1,
    const float* __restrict__ Wt2, const float* __restrict__ b2, const float* __restrict__ g2, const float* __restrict__ be2,
    const float* __restrict__ Wt3, const float* __restrict__ b3, const float* __restrict__ g3, const float* __restrict__ be3,
    const float* __restrict__ Wp, const float* __restrict__ bp,
    float* __restrict__ out)
{
    const int t = threadIdx.x, lane = t & 63, w = t >> 6;
    const int r = blockIdx.x * 4 + w;
    const int u = uidx[r], it = iidx[r];
    const float a_ui = A[(size_t)u * LDI + it];

    float ue = 0.f, ie = 0.f;
    for (int p0 = 0; p0 < NP; ++p0) ue += Upart[((size_t)p0 * B_N + r) * 64 + lane];
    for (int p0 = 0; p0 < NC; ++p0) ie += Cpart[((size_t)p0 * I_COLS + it) * 64 + lane];
    ue -= a_ui * WuT[(size_t)it * 64 + lane];
    ie -= a_ui * WiT[(size_t)u * 64 + lane];

    // layer 1: 128 -> 64, LN, ReLU
    float h = b1[lane];
    for (int c = 0; c < 64; ++c) h += __shfl(ue, c) * Wt1[c * 64 + lane];
    for (int c = 0; c < 64; ++c) h += __shfl(ie, c) * Wt1[(64 + c) * 64 + lane];
    {
        float m = redsum64(h) * (1.0f / 64.0f);
        float d = h - m;
        float v = redsum64(d * d) * (1.0f / 64.0f);
        h = d * rsqrtf(v + 1e-5f) * g1[lane] + be1[lane];
        h = fmaxf(h, 0.0f);
    }
    // layer 2: 64 -> 32
    const int l2 = lane & 31;
    float h2 = b2[l2];
    for (int c = 0; c < 64; ++c) h2 += __shfl(h, c) * Wt2[c * 32 + l2];
    {
        float m = redsum32(h2) * (1.0f / 32.0f);
        float d = h2 - m;
        float v = redsum32(d * d) * (1.0f / 32.0f);
        h2 = d * rsqrtf(v + 1e-5f) * g2[l2] + be2[l2];
        h2 = fmaxf(h2, 0.0f);
    }
    // layer 3: 32 -> 16
    const int l3 = lane & 15;
    float h3 = b3[l3];
    for (int c = 0; c < 32; ++c) h3 += __shfl(h2, c) * Wt3[c * 16 + l3];
    {
        float m = redsum16(h3) * (1.0f / 16.0f);
        float d = h3 - m;
        float v = redsum16(d * d) * (1.0f / 16.0f);
        h3 = d * rsqrtf(v + 1e-5f) * g3[l3] + be3[l3];
        h3 = fmaxf(h3, 0.0f);
    }
    float tt = h3 * Wp[l3];
    tt = redsum16(tt);
    if (lane == 0) out[r] = tt + bp[0];
}

extern "C" void kernel_launch(void* const* d_in, const int* in_sizes, int n_in,
                              void* d_out, int out_size, void* d_ws, size_t ws_size,
                              hipStream_t stream)
{
    const float* A    = (const float*)d_in[0];
    const int*   uidx = (const int*)d_in[1];
    const int*   iidx = (const int*)d_in[2];
    const float* W_u  = (const float*)d_in[3];
    const float* W_i  = (const float*)d_in[4];
    const float* W1   = (const float*)d_in[5];
    const float* b1   = (const float*)d_in[6];
    const float* g1   = (const float*)d_in[7];
    const float* be1  = (const float*)d_in[8];
    const float* W2   = (const float*)d_in[9];
    const float* b2   = (const float*)d_in[10];
    const float* g2   = (const float*)d_in[11];
    const float* be2  = (const float*)d_in[12];
    const float* W3   = (const float*)d_in[13];
    const float* b3   = (const float*)d_in[14];
    const float* g3   = (const float*)d_in[15];
    const float* be3  = (const float*)d_in[16];
    const float* Wp   = (const float*)d_in[17];
    const float* bp   = (const float*)d_in[18];
    float* out = (float*)d_out;

    unsigned short* Wtu_p = (unsigned short*)d_ws;          // SU_P*2048 bf16
    unsigned short* Wti_p = Wtu_p + (size_t)SU_P * 2048;    // SC*2048 bf16
    float* Wt1 = (float*)(Wti_p + (size_t)SC * 2048);       // 128*64
    float* Wt2 = Wt1 + 128 * 64;
    float* Wt3 = Wt2 + 64 * 32;
    float* WuT = Wt3 + 32 * 16;                             // I_COLS*64
    float* WiT = WuT + (size_t)I_COLS * 64;                 // U_ROWS*64
    float* Upart = WiT + (size_t)U_ROWS * 64;               // NP_U*B_N*64
    float* Cpart = Upart + (size_t)NP_U * B_N * 64;         // NC*I_COLS*64

    size_t fixed_b = (size_t)(SU_P + SC) * 2048 * 2
                   + (size_t)(128 * 64 + 64 * 32 + 32 * 16) * 4
                   + (size_t)(I_COLS + U_ROWS) * 64 * 4
                   + (size_t)NP_U * B_N * 64 * 4;
    int NC = 32;
    while (NC > 4 && fixed_b + (size_t)NC * I_COLS * 64 * 4 > ws_size) NC >>= 1;
    int spc = (SC + NC - 1) / NC;

    int prep_tot = (SU_P + SC) * 2048 + 64 * 128 + 32 * 64 + 16 * 32
                 + 64 * I_COLS + 64 * U_ROWS;
    hipLaunchKernelGGL(k_prep, dim3((prep_tot + 255) / 256), dim3(256), 0, stream,
                       W_u, W_i, Wtu_p, Wti_p, W1, W2, W3, Wt1, Wt2, Wt3, WuT, WiT);

    hipLaunchKernelGGL(k_gemm, dim3(NPAN * NC + 64 * NP_U), dim3(256), 0, stream,
                       A, uidx, Wtu_p, Wti_p, Upart, Cpart, NC, spc);

    hipLaunchKernelGGL(k_epi, dim3(B_N / 4), dim3(256), 0, stream,
                       A, uidx, iidx, Upart, Cpart, NP_U, NC,
                       WuT, WiT, Wt1, b1, g1, be1, Wt2, b2, g2, be2,
                       Wt3, b3, g3, be3, Wp, bp, out);
}

// Round 6
// 247.787 us; speedup vs baseline: 1.3907x; 1.3413x over previous
//
#include <hip/hip_runtime.h>

#define U_ROWS 20000
#define I_COLS 10000
#define LDI    10001
#define B_N    4096
#define SC     625        // c-gemm K-steps (20000/32)
#define NPAN_C 79         // c-gemm i-panels of 128 (ceil(10000/128))
#define NC_C   8          // c-gemm K-split
#define SUT    79         // u-gemm k-tiles of 128 (ceil(10000/128))
#define NP_U   8          // u-gemm K-split
#define SPU_T  10         // ceil(SUT/NP_U)
#define SU_P   316        // packed 32-k-steps for u-gemm (79*4)

typedef __attribute__((ext_vector_type(8))) __bf16 bf16x8;
typedef __attribute__((ext_vector_type(4))) float f32x4;

__device__ __forceinline__ unsigned short f2bf(float f) {
    unsigned int u = __float_as_uint(f);
    return (unsigned short)((u + 0x7FFFu + ((u >> 16) & 1u)) >> 16);  // RTN-even
}

// Fused prep: pack W_u/W_i into MFMA B-fragment order (bf16), transpose MLP
// weights, transposed WuT/WiT for the coalesced epilogue gather.
// Pack layout: out[((s*4+nb)*64 + l)*8 + j] = bf16(W[nb*16+(l&15)][s*32+(l>>4)*8+j])
__global__ __launch_bounds__(256) void k_prep(
    const float* __restrict__ Wu, const float* __restrict__ Wi,
    unsigned short* __restrict__ Pu, unsigned short* __restrict__ Pi,
    const float* __restrict__ W1, const float* __restrict__ W2, const float* __restrict__ W3,
    float* __restrict__ Wt1, float* __restrict__ Wt2, float* __restrict__ Wt3,
    float* __restrict__ WuT, float* __restrict__ WiT)
{
    const int NU = SU_P * 2048, NC2 = SC * 2048;
    int idx = blockIdx.x * 256 + threadIdx.x;
    if (idx < NU + NC2) {
        const float* W = (idx < NU) ? Wu : Wi;
        unsigned short* out = (idx < NU) ? Pu : Pi;
        int n_k = (idx < NU) ? I_COLS : U_ROWS;
        int li = (idx < NU) ? idx : idx - NU;
        int j  = li & 7;
        int l  = (li >> 3) & 63;
        int nb = (li >> 9) & 3;
        int s  = li >> 11;
        int n  = nb * 16 + (l & 15);
        int k  = s * 32 + ((l >> 4) << 3) + j;
        float v = (k < n_k) ? W[(size_t)n * n_k + k] : 0.0f;
        out[li] = f2bf(v);
        return;
    }
    int r2 = idx - (NU + NC2);
    if (r2 < 64 * 128) { int r = r2 / 128, c = r2 % 128; Wt1[c * 64 + r] = W1[r2]; return; }
    r2 -= 64 * 128;
    if (r2 < 32 * 64)  { int r = r2 / 64,  c = r2 % 64;  Wt2[c * 32 + r] = W2[r2]; return; }
    r2 -= 32 * 64;
    if (r2 < 16 * 32)  { int r = r2 / 32,  c = r2 % 32;  Wt3[c * 16 + r] = W3[r2]; return; }
    r2 -= 16 * 32;
    if (r2 < 64 * I_COLS) {
        int n = r2 / I_COLS, k = r2 % I_COLS;
        WuT[(size_t)k * 64 + n] = Wu[r2];
        return;
    }
    r2 -= 64 * I_COLS;
    if (r2 < 64 * U_ROWS) {
        int n = r2 / U_ROWS, u = r2 % U_ROWS;
        WiT[(size_t)u * 64 + n] = Wi[r2];
        return;
    }
}

// Fused GEMM. Staging rule: every global-load instruction is lane-contiguous
// (lanes span columns): per wave-instr = 2 rows x 512B contiguous each.
// A is packed to bf16 at stage time (A is 0/1 -> exact).
//  blocks [0, NPAN_C*NC_C):  c-gemm  Cpart[p][i][n] = sum_u A[u,i]*Wi[n,u]
//    LDS tile bf16 [32 k(u)][128 i], 8KB, swizzle byte ^= ((k>>3)&3)<<5.
//    Staged by 4 wave-instrs (rows r = q*8 + w*2 + half, q in [0,4)).
//  blocks [+, +64*NP_U):     u-gemm  Upart[p][r][n] = sum_i A[u_r,i]*Wu[n,i]
//    LDS tile bf16 [64 r][128 k], 16KB, swizzle byte ^= ((r&7)<<4).
//    Staged by 8 wave-instrs; read is ds_read_b128 -> direct MFMA operand.
__global__ __launch_bounds__(256) void k_gemm(
    const float* __restrict__ A, const int* __restrict__ uidx,
    const unsigned short* __restrict__ Bpu, const unsigned short* __restrict__ Bpc,
    float* __restrict__ Upart, float* __restrict__ Cpart,
    int spc)
{
    __shared__ char smem[64 * 256];     // 16 KB (u-path size; c uses 8 KB)
    const int t = threadIdx.x, lane = t & 63, w = t >> 6;
    const int rl = lane & 15, g = lane >> 4;
    const int half = lane >> 5, lc = lane & 31;
    const int CB = NPAN_C * NC_C;
    const char* Ab = (const char*)A;

    if ((int)blockIdx.x < CB) {
        // ---------------- c-gemm ----------------
        const int p = blockIdx.x % NC_C, mb = blockIdx.x / NC_C;
        const int i0 = mb * 128;
        const int s0 = p * spc;
        const int s1 = (SC < s0 + spc) ? SC : (s0 + spc);

        f32x4 acc[2][4];
#pragma unroll
        for (int mt = 0; mt < 2; ++mt)
#pragma unroll
            for (int nb = 0; nb < 4; ++nb) acc[mt][nb] = (f32x4)(0.0f);

        // staging: instr q (0..3): LDS k-row r = q*8 + w*2 + half, cols lc*4..+3
#define CROW(q) ((q) * 8 + w * 2 + half)
#define CLOADT(dst, S) do { \
        _Pragma("unroll") \
        for (int q_ = 0; q_ < 4; ++q_) { \
            size_t gr_ = (size_t)((S) * 32 + CROW(q_)) * LDI + i0 + lc * 4; \
            dst[q_] = *(const f32x4*)(Ab + gr_ * 4); \
        } } while (0)

        f32x4 av[4];
        CLOADT(av, s0);
        for (int s = s0; s < s1; ++s) {
            __syncthreads();            // prev step's LDS reads done
#pragma unroll
            for (int q = 0; q < 4; ++q) {
                int r = CROW(q);
                unsigned int lo = __builtin_amdgcn_perm(__float_as_uint(av[q][1]),
                                                        __float_as_uint(av[q][0]), 0x07060302);
                unsigned int hi = __builtin_amdgcn_perm(__float_as_uint(av[q][3]),
                                                        __float_as_uint(av[q][2]), 0x07060302);
                uint2 v2; v2.x = lo; v2.y = hi;
                *(uint2*)(smem + r * 256 + ((lc * 8) ^ (((r >> 3) & 3) << 5))) = v2;
            }
            __syncthreads();            // tile visible
            if (s + 1 < s1) CLOADT(av, s + 1);

            bf16x8 bv[4];
#pragma unroll
            for (int nb = 0; nb < 4; ++nb)
                bv[nb] = *(const bf16x8*)(Bpc + ((size_t)(s * 4 + nb) * 64 + lane) * 8);

#pragma unroll
            for (int mt = 0; mt < 2; ++mt) {
                const char* rp = smem + (((w * 32 + mt * 16 + rl) * 2) ^ (g << 5));
                unsigned int pr[4];
#pragma unroll
                for (int q = 0; q < 4; ++q) {
                    unsigned int e0 = *(const unsigned short*)(rp + (g * 8 + 2 * q) * 256);
                    unsigned int e1 = *(const unsigned short*)(rp + (g * 8 + 2 * q + 1) * 256);
                    pr[q] = e0 | (e1 << 16);
                }
                union { unsigned int i[4]; bf16x8 v; } af;
                af.i[0] = pr[0]; af.i[1] = pr[1]; af.i[2] = pr[2]; af.i[3] = pr[3];
#pragma unroll
                for (int nb = 0; nb < 4; ++nb)
                    acc[mt][nb] = __builtin_amdgcn_mfma_f32_16x16x32_bf16(af.v, bv[nb], acc[mt][nb], 0, 0, 0);
            }
        }

        float* outp = Cpart + (size_t)p * I_COLS * 64;
#pragma unroll
        for (int mt = 0; mt < 2; ++mt)
#pragma unroll
            for (int nb = 0; nb < 4; ++nb)
#pragma unroll
                for (int reg = 0; reg < 4; ++reg) {
                    int i = i0 + w * 32 + mt * 16 + g * 4 + reg;
                    if (i < I_COLS) outp[(size_t)i * 64 + nb * 16 + rl] = acc[mt][nb][reg];
                }
    } else {
        // ---------------- u-gemm ----------------
        const int bid = blockIdx.x - CB;
        const int p = bid % NP_U, mb = bid / NP_U;
        const int r0 = mb * 64;
        const int s0 = p * SPU_T;
        const int s1 = (SUT < s0 + SPU_T) ? SUT : (s0 + SPU_T);

        int ur[8];
#pragma unroll
        for (int q = 0; q < 8; ++q) ur[q] = uidx[r0 + (q * 4 + w) * 2 + half];

        f32x4 acc[4];
#pragma unroll
        for (int nb = 0; nb < 4; ++nb) acc[nb] = (f32x4)(0.0f);

#define ULOADT(dst, S) do { \
        _Pragma("unroll") \
        for (int q_ = 0; q_ < 8; ++q_) { \
            size_t ad_ = (size_t)ur[q_] * LDI + (S) * 128 + lc * 4; \
            dst[q_] = *(const f32x4*)(Ab + ad_ * 4); \
        } } while (0)

        f32x4 av[8];
        ULOADT(av, s0);
        for (int s = s0; s < s1; ++s) {
            __syncthreads();
#pragma unroll
            for (int q = 0; q < 8; ++q) {
                int r = (q * 4 + w) * 2 + half;
                unsigned int lo = __builtin_amdgcn_perm(__float_as_uint(av[q][1]),
                                                        __float_as_uint(av[q][0]), 0x07060302);
                unsigned int hi = __builtin_amdgcn_perm(__float_as_uint(av[q][3]),
                                                        __float_as_uint(av[q][2]), 0x07060302);
                uint2 v2; v2.x = lo; v2.y = hi;
                *(uint2*)(smem + r * 256 + ((lc * 8) ^ ((r & 7) << 4))) = v2;
            }
            __syncthreads();
            if (s + 1 < s1) ULOADT(av, s + 1);

            const int r_loc = w * 16 + rl;
            const char* rp = smem + r_loc * 256;
            const int rm = (r_loc & 7) << 4;
#pragma unroll
            for (int ks = 0; ks < 4; ++ks) {
                const int kk = s * 4 + ks;
                bf16x8 afv = *(const bf16x8*)(rp + ((ks * 64 + g * 16) ^ rm));
                bf16x8 bv[4];
#pragma unroll
                for (int nb = 0; nb < 4; ++nb)
                    bv[nb] = *(const bf16x8*)(Bpu + ((size_t)(kk * 4 + nb) * 64 + lane) * 8);
#pragma unroll
                for (int nb = 0; nb < 4; ++nb)
                    acc[nb] = __builtin_amdgcn_mfma_f32_16x16x32_bf16(afv, bv[nb], acc[nb], 0, 0, 0);
            }
        }

        float* outp = Upart + (size_t)p * B_N * 64;
#pragma unroll
        for (int nb = 0; nb < 4; ++nb)
#pragma unroll
            for (int reg = 0; reg < 4; ++reg) {
                int r = r0 + w * 16 + g * 4 + reg;
                outp[(size_t)r * 64 + nb * 16 + rl] = acc[nb][reg];
            }
    }
}

__device__ __forceinline__ float redsum64(float x) {
    x += __shfl_xor(x, 1);  x += __shfl_xor(x, 2);  x += __shfl_xor(x, 4);
    x += __shfl_xor(x, 8);  x += __shfl_xor(x, 16); x += __shfl_xor(x, 32);
    return x;
}
__device__ __forceinline__ float redsum32(float x) {
    x += __shfl_xor(x, 1); x += __shfl_xor(x, 2); x += __shfl_xor(x, 4);
    x += __shfl_xor(x, 8); x += __shfl_xor(x, 16);
    return x;
}
__device__ __forceinline__ float redsum16(float x) {
    x += __shfl_xor(x, 1); x += __shfl_xor(x, 2); x += __shfl_xor(x, 4);
    x += __shfl_xor(x, 8);
    return x;
}

// one wave per batch row: reduce partials, mask corrections, full MLP
__global__ __launch_bounds__(256) void k_epi(
    const float* __restrict__ A, const int* __restrict__ uidx, const int* __restrict__ iidx,
    const float* __restrict__ Upart, const float* __restrict__ Cpart, int NP, int NC,
    const float* __restrict__ WuT, const float* __restrict__ WiT,
    const float* __restrict__ Wt1, const float* __restrict__ b1, const float* __restrict__ g1, const float* __restrict__ be1,
    const float* __restrict__ Wt2, const float* __restrict__ b2, const float* __restrict__ g2, const float* __restrict__ be2,
    const float* __restrict__ Wt3, const float* __restrict__ b3, const float* __restrict__ g3, const float* __restrict__ be3,
    const float* __restrict__ Wp, const float* __restrict__ bp,
    float* __restrict__ out)
{
    const int t = threadIdx.x, lane = t & 63, w = t >> 6;
    const int r = blockIdx.x * 4 + w;
    const int u = uidx[r], it = iidx[r];
    const float a_ui = A[(size_t)u * LDI + it];

    float ue = 0.f, ie = 0.f;
    for (int p0 = 0; p0 < NP; ++p0) ue += Upart[((size_t)p0 * B_N + r) * 64 + lane];
    for (int p0 = 0; p0 < NC; ++p0) ie += Cpart[((size_t)p0 * I_COLS + it) * 64 + lane];
    ue -= a_ui * WuT[(size_t)it * 64 + lane];
    ie -= a_ui * WiT[(size_t)u * 64 + lane];

    // layer 1: 128 -> 64, LN, ReLU
    float h = b1[lane];
    for (int c = 0; c < 64; ++c) h += __shfl(ue, c) * Wt1[c * 64 + lane];
    for (int c = 0; c < 64; ++c) h += __shfl(ie, c) * Wt1[(64 + c) * 64 + lane];
    {
        float m = redsum64(h) * (1.0f / 64.0f);
        float d = h - m;
        float v = redsum64(d * d) * (1.0f / 64.0f);
        h = d * rsqrtf(v + 1e-5f) * g1[lane] + be1[lane];
        h = fmaxf(h, 0.0f);
    }
    // layer 2: 64 -> 32
    const int l2 = lane & 31;
    float h2 = b2[l2];
    for (int c = 0; c < 64; ++c) h2 += __shfl(h, c) * Wt2[c * 32 + l2];
    {
        float m = redsum32(h2) * (1.0f / 32.0f);
        float d = h2 - m;
        float v = redsum32(d * d) * (1.0f / 32.0f);
        h2 = d * rsqrtf(v + 1e-5f) * g2[l2] + be2[l2];
        h2 = fmaxf(h2, 0.0f);
    }
    // layer 3: 32 -> 16
    const int l3 = lane & 15;
    float h3 = b3[l3];
    for (int c = 0; c < 32; ++c) h3 += __shfl(h2, c) * Wt3[c * 16 + l3];
    {
        float m = redsum16(h3) * (1.0f / 16.0f);
        float d = h3 - m;
        float v = redsum16(d * d) * (1.0f / 16.0f);
        h3 = d * rsqrtf(v + 1e-5f) * g3[l3] + be3[l3];
        h3 = fmaxf(h3, 0.0f);
    }
    float tt = h3 * Wp[l3];
    tt = redsum16(tt);
    if (lane == 0) out[r] = tt + bp[0];
}

extern "C" void kernel_launch(void* const* d_in, const int* in_sizes, int n_in,
                              void* d_out, int out_size, void* d_ws, size_t ws_size,
                              hipStream_t stream)
{
    const float* A    = (const float*)d_in[0];
    const int*   uidx = (const int*)d_in[1];
    const int*   iidx = (const int*)d_in[2];
    const float* W_u  = (const float*)d_in[3];
    const float* W_i  = (const float*)d_in[4];
    const float* W1   = (const float*)d_in[5];
    const float* b1   = (const float*)d_in[6];
    const float* g1   = (const float*)d_in[7];
    const float* be1  = (const float*)d_in[8];
    const float* W2   = (const float*)d_in[9];
    const float* b2   = (const float*)d_in[10];
    const float* g2   = (const float*)d_in[11];
    const float* be2  = (const float*)d_in[12];
    const float* W3   = (const float*)d_in[13];
    const float* b3   = (const float*)d_in[14];
    const float* g3   = (const float*)d_in[15];
    const float* be3  = (const float*)d_in[16];
    const float* Wp   = (const float*)d_in[17];
    const float* bp   = (const float*)d_in[18];
    float* out = (float*)d_out;

    unsigned short* Wtu_p = (unsigned short*)d_ws;          // SU_P*2048 bf16
    unsigned short* Wti_p = Wtu_p + (size_t)SU_P * 2048;    // SC*2048 bf16
    float* Wt1 = (float*)(Wti_p + (size_t)SC * 2048);       // 128*64
    float* Wt2 = Wt1 + 128 * 64;
    float* Wt3 = Wt2 + 64 * 32;
    float* WuT = Wt3 + 32 * 16;                             // I_COLS*64
    float* WiT = WuT + (size_t)I_COLS * 64;                 // U_ROWS*64
    float* Upart = WiT + (size_t)U_ROWS * 64;               // NP_U*B_N*64
    float* Cpart = Upart + (size_t)NP_U * B_N * 64;         // NC_C*I_COLS*64

    int spc = (SC + NC_C - 1) / NC_C;

    int prep_tot = (SU_P + SC) * 2048 + 64 * 128 + 32 * 64 + 16 * 32
                 + 64 * I_COLS + 64 * U_ROWS;
    hipLaunchKernelGGL(k_prep, dim3((prep_tot + 255) / 256), dim3(256), 0, stream,
                       W_u, W_i, Wtu_p, Wti_p, W1, W2, W3, Wt1, Wt2, Wt3, WuT, WiT);

    hipLaunchKernelGGL(k_gemm, dim3(NPAN_C * NC_C + 64 * NP_U), dim3(256), 0, stream,
                       A, uidx, Wtu_p, Wti_p, Upart, Cpart, spc);

    hipLaunchKernelGGL(k_epi, dim3(B_N / 4), dim3(256), 0, stream,
                       A, uidx, iidx, Upart, Cpart, NP_U, NC_C,
                       WuT, WiT, Wt1, b1, g1, be1, Wt2, b2, g2, be2,
                       Wt3, b3, g3, be3, Wp, bp, out);
}

// Round 7
// 246.653 us; speedup vs baseline: 1.3971x; 1.0046x over previous
//
#include <hip/hip_runtime.h>

#define U_ROWS 20000
#define I_COLS 10000
#define LDI    10001
#define B_N    4096
#define SC     625        // c-gemm K-steps (20000/32)
#define NPAN_C 79         // c-gemm i-panels of 128 (ceil(10000/128))
#define NC_C   8          // c-gemm K-split
#define SUT    79         // u-gemm k-tiles of 128 (ceil(10000/128))
#define NP_U   8          // u-gemm K-split
#define SPU_T  10         // ceil(SUT/NP_U)
#define SU_P   316        // packed 32-k-steps for u-gemm (79*4)

typedef __attribute__((ext_vector_type(8))) __bf16 bf16x8;
typedef __attribute__((ext_vector_type(4))) float f32x4;

__device__ __forceinline__ unsigned short f2bf(float f) {
    unsigned int u = __float_as_uint(f);
    return (unsigned short)((u + 0x7FFFu + ((u >> 16) & 1u)) >> 16);  // RTN-even
}

// Fused prep: pack W_u/W_i into MFMA B-fragment order (bf16), transpose MLP
// weights, transposed WuT/WiT for the coalesced epilogue gather.
// Pack layout: out[((s*4+nb)*64 + l)*8 + j] = bf16(W[nb*16+(l&15)][s*32+(l>>4)*8+j])
__global__ __launch_bounds__(256) void k_prep(
    const float* __restrict__ Wu, const float* __restrict__ Wi,
    unsigned short* __restrict__ Pu, unsigned short* __restrict__ Pi,
    const float* __restrict__ W1, const float* __restrict__ W2, const float* __restrict__ W3,
    float* __restrict__ Wt1, float* __restrict__ Wt2, float* __restrict__ Wt3,
    float* __restrict__ WuT, float* __restrict__ WiT)
{
    const int NU = SU_P * 2048, NC2 = SC * 2048;
    int idx = blockIdx.x * 256 + threadIdx.x;
    if (idx < NU + NC2) {
        const float* W = (idx < NU) ? Wu : Wi;
        unsigned short* out = (idx < NU) ? Pu : Pi;
        int n_k = (idx < NU) ? I_COLS : U_ROWS;
        int li = (idx < NU) ? idx : idx - NU;
        int j  = li & 7;
        int l  = (li >> 3) & 63;
        int nb = (li >> 9) & 3;
        int s  = li >> 11;
        int n  = nb * 16 + (l & 15);
        int k  = s * 32 + ((l >> 4) << 3) + j;
        float v = (k < n_k) ? W[(size_t)n * n_k + k] : 0.0f;
        out[li] = f2bf(v);
        return;
    }
    int r2 = idx - (NU + NC2);
    if (r2 < 64 * 128) { int r = r2 / 128, c = r2 % 128; Wt1[c * 64 + r] = W1[r2]; return; }
    r2 -= 64 * 128;
    if (r2 < 32 * 64)  { int r = r2 / 64,  c = r2 % 64;  Wt2[c * 32 + r] = W2[r2]; return; }
    r2 -= 32 * 64;
    if (r2 < 16 * 32)  { int r = r2 / 32,  c = r2 % 32;  Wt3[c * 16 + r] = W3[r2]; return; }
    r2 -= 16 * 32;
    if (r2 < 64 * I_COLS) {
        int n = r2 / I_COLS, k = r2 % I_COLS;
        WuT[(size_t)k * 64 + n] = Wu[r2];
        return;
    }
    r2 -= 64 * I_COLS;
    if (r2 < 64 * U_ROWS) {
        int n = r2 / U_ROWS, u = r2 % U_ROWS;
        WiT[(size_t)u * 64 + n] = Wi[r2];
        return;
    }
}

// Fused GEMM. Staging: lane-contiguous wave-instrs (2 rows x 512B each);
// A packed to bf16 at stage time (0/1 -> exact).
//  c-gemm: 2-DEEP register prefetch (avA/avB, load-to-use = 2 steps) to keep
//          ~2 tile-loads (32KB/block) continuously outstanding.
//  u-gemm: 1-deep (unchanged; keeps fused-kernel VGPR <= 128).
__global__ __launch_bounds__(256) void k_gemm(
    const float* __restrict__ A, const int* __restrict__ uidx,
    const unsigned short* __restrict__ Bpu, const unsigned short* __restrict__ Bpc,
    float* __restrict__ Upart, float* __restrict__ Cpart,
    int spc)
{
    __shared__ char smem[64 * 256];     // 16 KB (u-path size; c uses 8 KB)
    const int t = threadIdx.x, lane = t & 63, w = t >> 6;
    const int rl = lane & 15, g = lane >> 4;
    const int half = lane >> 5, lc = lane & 31;
    const int CB = NPAN_C * NC_C;
    const char* Ab = (const char*)A;

    if ((int)blockIdx.x < CB) {
        // ---------------- c-gemm ----------------
        const int p = blockIdx.x % NC_C, mb = blockIdx.x / NC_C;
        const int i0 = mb * 128;
        const int s0 = p * spc;
        const int s1 = (SC < s0 + spc) ? SC : (s0 + spc);

        f32x4 acc[2][4];
#pragma unroll
        for (int mt = 0; mt < 2; ++mt)
#pragma unroll
            for (int nb = 0; nb < 4; ++nb) acc[mt][nb] = (f32x4)(0.0f);

        // staging: instr q (0..3): LDS k-row r = q*8 + w*2 + half, cols lc*4..+3
#define CROW(q) ((q) * 8 + w * 2 + half)
#define CLOADT(dst, S) do { \
        _Pragma("unroll") \
        for (int q_ = 0; q_ < 4; ++q_) { \
            size_t gr_ = (size_t)((S) * 32 + CROW(q_)) * LDI + i0 + lc * 4; \
            dst[q_] = *(const f32x4*)(Ab + gr_ * 4); \
        } } while (0)

#define CWRITE(src) do { \
        _Pragma("unroll") \
        for (int q_ = 0; q_ < 4; ++q_) { \
            int r_ = CROW(q_); \
            unsigned int lo_ = __builtin_amdgcn_perm(__float_as_uint(src[q_][1]), \
                                                     __float_as_uint(src[q_][0]), 0x07060302); \
            unsigned int hi_ = __builtin_amdgcn_perm(__float_as_uint(src[q_][3]), \
                                                     __float_as_uint(src[q_][2]), 0x07060302); \
            uint2 v2_; v2_.x = lo_; v2_.y = hi_; \
            *(uint2*)(smem + r_ * 256 + ((lc * 8) ^ (((r_ >> 3) & 3) << 5))) = v2_; \
        } } while (0)

#define CCOMPUTE(S) do { \
        bf16x8 bv_[4]; \
        _Pragma("unroll") \
        for (int nb_ = 0; nb_ < 4; ++nb_) \
            bv_[nb_] = *(const bf16x8*)(Bpc + ((size_t)((S) * 4 + nb_) * 64 + lane) * 8); \
        _Pragma("unroll") \
        for (int mt_ = 0; mt_ < 2; ++mt_) { \
            const char* rp_ = smem + (((w * 32 + mt_ * 16 + rl) * 2) ^ (g << 5)); \
            unsigned int pr_[4]; \
            _Pragma("unroll") \
            for (int q_ = 0; q_ < 4; ++q_) { \
                unsigned int e0_ = *(const unsigned short*)(rp_ + (g * 8 + 2 * q_) * 256); \
                unsigned int e1_ = *(const unsigned short*)(rp_ + (g * 8 + 2 * q_ + 1) * 256); \
                pr_[q_] = e0_ | (e1_ << 16); \
            } \
            union { unsigned int i[4]; bf16x8 v; } af_; \
            af_.i[0] = pr_[0]; af_.i[1] = pr_[1]; af_.i[2] = pr_[2]; af_.i[3] = pr_[3]; \
            _Pragma("unroll") \
            for (int nb_ = 0; nb_ < 4; ++nb_) \
                acc[mt_][nb_] = __builtin_amdgcn_mfma_f32_16x16x32_bf16(af_.v, bv_[nb_], acc[mt_][nb_], 0, 0, 0); \
        } } while (0)

        f32x4 avA[4], avB[4];
        CLOADT(avA, s0);
        if (s0 + 1 < s1) CLOADT(avB, s0 + 1);

        int s = s0;
        for (; s + 1 < s1; s += 2) {
            __syncthreads();
            CWRITE(avA);
            __syncthreads();
            if (s + 2 < s1) CLOADT(avA, s + 2);
            CCOMPUTE(s);
            __syncthreads();
            CWRITE(avB);
            __syncthreads();
            if (s + 3 < s1) CLOADT(avB, s + 3);
            CCOMPUTE(s + 1);
        }
        if (s < s1) {
            __syncthreads();
            CWRITE(avA);
            __syncthreads();
            CCOMPUTE(s);
        }

        float* outp = Cpart + (size_t)p * I_COLS * 64;
#pragma unroll
        for (int mt = 0; mt < 2; ++mt)
#pragma unroll
            for (int nb = 0; nb < 4; ++nb)
#pragma unroll
                for (int reg = 0; reg < 4; ++reg) {
                    int i = i0 + w * 32 + mt * 16 + g * 4 + reg;
                    if (i < I_COLS) outp[(size_t)i * 64 + nb * 16 + rl] = acc[mt][nb][reg];
                }
    } else {
        // ---------------- u-gemm (unchanged, 1-deep) ----------------
        const int bid = blockIdx.x - CB;
        const int p = bid % NP_U, mb = bid / NP_U;
        const int r0 = mb * 64;
        const int s0 = p * SPU_T;
        const int s1 = (SUT < s0 + SPU_T) ? SUT : (s0 + SPU_T);

        int ur[8];
#pragma unroll
        for (int q = 0; q < 8; ++q) ur[q] = uidx[r0 + (q * 4 + w) * 2 + half];

        f32x4 acc[4];
#pragma unroll
        for (int nb = 0; nb < 4; ++nb) acc[nb] = (f32x4)(0.0f);

#define ULOADT(dst, S) do { \
        _Pragma("unroll") \
        for (int q_ = 0; q_ < 8; ++q_) { \
            size_t ad_ = (size_t)ur[q_] * LDI + (S) * 128 + lc * 4; \
            dst[q_] = *(const f32x4*)(Ab + ad_ * 4); \
        } } while (0)

        f32x4 av[8];
        ULOADT(av, s0);
        for (int s = s0; s < s1; ++s) {
            __syncthreads();
#pragma unroll
            for (int q = 0; q < 8; ++q) {
                int r = (q * 4 + w) * 2 + half;
                unsigned int lo = __builtin_amdgcn_perm(__float_as_uint(av[q][1]),
                                                        __float_as_uint(av[q][0]), 0x07060302);
                unsigned int hi = __builtin_amdgcn_perm(__float_as_uint(av[q][3]),
                                                        __float_as_uint(av[q][2]), 0x07060302);
                uint2 v2; v2.x = lo; v2.y = hi;
                *(uint2*)(smem + r * 256 + ((lc * 8) ^ ((r & 7) << 4))) = v2;
            }
            __syncthreads();
            if (s + 1 < s1) ULOADT(av, s + 1);

            const int r_loc = w * 16 + rl;
            const char* rp = smem + r_loc * 256;
            const int rm = (r_loc & 7) << 4;
#pragma unroll
            for (int ks = 0; ks < 4; ++ks) {
                const int kk = s * 4 + ks;
                bf16x8 afv = *(const bf16x8*)(rp + ((ks * 64 + g * 16) ^ rm));
                bf16x8 bv[4];
#pragma unroll
                for (int nb = 0; nb < 4; ++nb)
                    bv[nb] = *(const bf16x8*)(Bpu + ((size_t)(kk * 4 + nb) * 64 + lane) * 8);
#pragma unroll
                for (int nb = 0; nb < 4; ++nb)
                    acc[nb] = __builtin_amdgcn_mfma_f32_16x16x32_bf16(afv, bv[nb], acc[nb], 0, 0, 0);
            }
        }

        float* outp = Upart + (size_t)p * B_N * 64;
#pragma unroll
        for (int nb = 0; nb < 4; ++nb)
#pragma unroll
            for (int reg = 0; reg < 4; ++reg) {
                int r = r0 + w * 16 + g * 4 + reg;
                outp[(size_t)r * 64 + nb * 16 + rl] = acc[nb][reg];
            }
    }
}

__device__ __forceinline__ float redsum64(float x) {
    x += __shfl_xor(x, 1);  x += __shfl_xor(x, 2);  x += __shfl_xor(x, 4);
    x += __shfl_xor(x, 8);  x += __shfl_xor(x, 16); x += __shfl_xor(x, 32);
    return x;
}
__device__ __forceinline__ float redsum32(float x) {
    x += __shfl_xor(x, 1); x += __shfl_xor(x, 2); x += __shfl_xor(x, 4);
    x += __shfl_xor(x, 8); x += __shfl_xor(x, 16);
    return x;
}
__device__ __forceinline__ float redsum16(float x) {
    x += __shfl_xor(x, 1); x += __shfl_xor(x, 2); x += __shfl_xor(x, 4);
    x += __shfl_xor(x, 8);
    return x;
}

// one wave per batch row: reduce partials, mask corrections, full MLP
__global__ __launch_bounds__(256) void k_epi(
    const float* __restrict__ A, const int* __restrict__ uidx, const int* __restrict__ iidx,
    const float* __restrict__ Upart, const float* __restrict__ Cpart, int NP, int NC,
    const float* __restrict__ WuT, const float* __restrict__ WiT,
    const float* __restrict__ Wt1, const float* __restrict__ b1, const float* __restrict__ g1, const float* __restrict__ be1,
    const float* __restrict__ Wt2, const float* __restrict__ b2, const float* __restrict__ g2, const float* __restrict__ be2,
    const float* __restrict__ Wt3, const float* __restrict__ b3, const float* __restrict__ g3, const float* __restrict__ be3,
    const float* __restrict__ Wp, const float* __restrict__ bp,
    float* __restrict__ out)
{
    const int t = threadIdx.x, lane = t & 63, w = t >> 6;
    const int r = blockIdx.x * 4 + w;
    const int u = uidx[r], it = iidx[r];
    const float a_ui = A[(size_t)u * LDI + it];

    float ue = 0.f, ie = 0.f;
    for (int p0 = 0; p0 < NP; ++p0) ue += Upart[((size_t)p0 * B_N + r) * 64 + lane];
    for (int p0 = 0; p0 < NC; ++p0) ie += Cpart[((size_t)p0 * I_COLS + it) * 64 + lane];
    ue -= a_ui * WuT[(size_t)it * 64 + lane];
    ie -= a_ui * WiT[(size_t)u * 64 + lane];

    // layer 1: 128 -> 64, LN, ReLU
    float h = b1[lane];
    for (int c = 0; c < 64; ++c) h += __shfl(ue, c) * Wt1[c * 64 + lane];
    for (int c = 0; c < 64; ++c) h += __shfl(ie, c) * Wt1[(64 + c) * 64 + lane];
    {
        float m = redsum64(h) * (1.0f / 64.0f);
        float d = h - m;
        float v = redsum64(d * d) * (1.0f / 64.0f);
        h = d * rsqrtf(v + 1e-5f) * g1[lane] + be1[lane];
        h = fmaxf(h, 0.0f);
    }
    // layer 2: 64 -> 32
    const int l2 = lane & 31;
    float h2 = b2[l2];
    for (int c = 0; c < 64; ++c) h2 += __shfl(h, c) * Wt2[c * 32 + l2];
    {
        float m = redsum32(h2) * (1.0f / 32.0f);
        float d = h2 - m;
        float v = redsum32(d * d) * (1.0f / 32.0f);
        h2 = d * rsqrtf(v + 1e-5f) * g2[l2] + be2[l2];
        h2 = fmaxf(h2, 0.0f);
    }
    // layer 3: 32 -> 16
    const int l3 = lane & 15;
    float h3 = b3[l3];
    for (int c = 0; c < 32; ++c) h3 += __shfl(h2, c) * Wt3[c * 16 + l3];
    {
        float m = redsum16(h3) * (1.0f / 16.0f);
        float d = h3 - m;
        float v = redsum16(d * d) * (1.0f / 16.0f);
        h3 = d * rsqrtf(v + 1e-5f) * g3[l3] + be3[l3];
        h3 = fmaxf(h3, 0.0f);
    }
    float tt = h3 * Wp[l3];
    tt = redsum16(tt);
    if (lane == 0) out[r] = tt + bp[0];
}

extern "C" void kernel_launch(void* const* d_in, const int* in_sizes, int n_in,
                              void* d_out, int out_size, void* d_ws, size_t ws_size,
                              hipStream_t stream)
{
    const float* A    = (const float*)d_in[0];
    const int*   uidx = (const int*)d_in[1];
    const int*   iidx = (const int*)d_in[2];
    const float* W_u  = (const float*)d_in[3];
    const float* W_i  = (const float*)d_in[4];
    const float* W1   = (const float*)d_in[5];
    const float* b1   = (const float*)d_in[6];
    const float* g1   = (const float*)d_in[7];
    const float* be1  = (const float*)d_in[8];
    const float* W2   = (const float*)d_in[9];
    const float* b2   = (const float*)d_in[10];
    const float* g2   = (const float*)d_in[11];
    const float* be2  = (const float*)d_in[12];
    const float* W3   = (const float*)d_in[13];
    const float* b3   = (const float*)d_in[14];
    const float* g3   = (const float*)d_in[15];
    const float* be3  = (const float*)d_in[16];
    const float* Wp   = (const float*)d_in[17];
    const float* bp   = (const float*)d_in[18];
    float* out = (float*)d_out;

    unsigned short* Wtu_p = (unsigned short*)d_ws;          // SU_P*2048 bf16
    unsigned short* Wti_p = Wtu_p + (size_t)SU_P * 2048;    // SC*2048 bf16
    float* Wt1 = (float*)(Wti_p + (size_t)SC * 2048);       // 128*64
    float* Wt2 = Wt1 + 128 * 64;
    float* Wt3 = Wt2 + 64 * 32;
    float* WuT = Wt3 + 32 * 16;                             // I_COLS*64
    float* WiT = WuT + (size_t)I_COLS * 64;                 // U_ROWS*64
    float* Upart = WiT + (size_t)U_ROWS * 64;               // NP_U*B_N*64
    float* Cpart = Upart + (size_t)NP_U * B_N * 64;         // NC_C*I_COLS*64

    int spc = (SC + NC_C - 1) / NC_C;

    int prep_tot = (SU_P + SC) * 2048 + 64 * 128 + 32 * 64 + 16 * 32
                 + 64 * I_COLS + 64 * U_ROWS;
    hipLaunchKernelGGL(k_prep, dim3((prep_tot + 255) / 256), dim3(256), 0, stream,
                       W_u, W_i, Wtu_p, Wti_p, W1, W2, W3, Wt1, Wt2, Wt3, WuT, WiT);

    hipLaunchKernelGGL(k_gemm, dim3(NPAN_C * NC_C + 64 * NP_U), dim3(256), 0, stream,
                       A, uidx, Wtu_p, Wti_p, Upart, Cpart, spc);

    hipLaunchKernelGGL(k_epi, dim3(B_N / 4), dim3(256), 0, stream,
                       A, uidx, iidx, Upart, Cpart, NP_U, NC_C,
                       WuT, WiT, Wt1, b1, g1, be1, Wt2, b2, g2, be2,
                       Wt3, b3, g3, be3, Wp, bp, out);
}